// Round 11
// baseline (169.956 us; speedup 1.0000x reference)
//
#include <hip/hip_runtime.h>

// KnowledgeEmbedding loss via bf16 MFMA GEMMs, two-phase:
//  ke_prep (1088 blocks, 8 threads/row):
//    blocks [0,1024): A-table [rel][4096][136] = bf16(head[h]+rvec), k100=bias[t],
//                     pad 0  -- AND fused positive term: the same threads also
//                     gather tail[t] fp32, dot with (head+rvec) in registers,
//                     softplus(-pos-bias) -> width-8 shuffle -> LDS atomic ->
//                     one global atomicAdd per block.
//    blocks [1024,1088): B-table [rel][256][136] = bf16(tail[neg]), k100=1.0.
//  ke_main (1024 blocks): 64x128 tile GEMM from the dense tables (contiguous
//    16B/lane staging), 16x16x32 bf16 MFMA, PITCH=136 conflict-free LDS,
//    bias folded at k=100 -> layout-agnostic softplus-sum. No pos, no gathers.
// HISTORY: R10's prep ran at 136 blocks (half the CUs idle, 1 thr/row) ->
// ~25-30 us; this prep is 8x wider with coalesced 64B/lane-group loads.
// R9: scattered staging in-kernel = 37 us. R7 best single-phase ~30 us.
// PITCH=136 (68 words == 4 mod 32): uniform 8 words/bank (R8 fixed 5.9M
// conflict cycles of PITCH=128).

#define EMBED   100
#define BATCH   4096
#define NUM_NEG 256
#define BM      64
#define BN      128
#define PITCH   136

typedef __attribute__((ext_vector_type(8))) short s8;
typedef __attribute__((ext_vector_type(4))) short s4;
typedef __attribute__((ext_vector_type(4))) float f4;

struct RelP {
    const float* head;
    const float* tail;
    const float* bias;
    int hc, tc;
};

struct Params {
    RelP rel[8];
    const float* rel_vecs;
    const int*   batch_idxs;
    const int*   neg_idxs;
    float*       out;
};

__device__ __forceinline__ float softplus_f(float x) {
    float e = __expf(-fabsf(x));
    return fmaxf(x, 0.0f) + __logf(1.0f + e);
}

__device__ __forceinline__ unsigned short bf16_rne(float f) {
    unsigned u = __float_as_uint(f);
    u += 0x7FFFu + ((u >> 16) & 1u);
    return (unsigned short)(u >> 16);
}

__device__ __forceinline__ s8 pack8(float4 f0, float4 f1) {
    s8 v = { (short)bf16_rne(f0.x), (short)bf16_rne(f0.y),
             (short)bf16_rne(f0.z), (short)bf16_rne(f0.w),
             (short)bf16_rne(f1.x), (short)bf16_rne(f1.y),
             (short)bf16_rne(f1.z), (short)bf16_rne(f1.w) };
    return v;
}

// ---- phase 1: table build + fused positive term ----
__launch_bounds__(256, 8)
__global__ void ke_prep(Params p, short* aws, short* bws) {
    const int blk = blockIdx.x;
    const int tid = threadIdx.x;
    const int sub = tid & 7;

    if (blk < 1024) {
        // ---- A-table + positive term: 32 rows/block, 8 threads/row ----
        __shared__ float psum;
        if (tid == 0) psum = 0.0f;
        __syncthreads();

        const int row  = blk * 32 + (tid >> 3);      // [rel*4096 + brow]
        const int r    = row >> 12;
        const int brow = row & 4095;
        const RelP rp = p.rel[r];
        const int h = p.batch_idxs[brow * 8 + rp.hc];
        const int t = p.batch_idxs[brow * 8 + rp.tc];
        const float4* hp = (const float4*)(rp.head + (size_t)h * EMBED);
        const float4* tp = (const float4*)(rp.tail + (size_t)t * EMBED);
        const float4* rv = (const float4*)(p.rel_vecs + r * EMBED);
        short* dst = aws + (size_t)row * PITCH;

        float partial = 0.0f;
        if (sub < 6) {
            const int b4 = sub * 4;                  // float4 index base
            float4 e0 = hp[b4 + 0], e1 = hp[b4 + 1], e2 = hp[b4 + 2], e3 = hp[b4 + 3];
            const float4 r0 = rv[b4 + 0], r1 = rv[b4 + 1], r2 = rv[b4 + 2], r3 = rv[b4 + 3];
            e0.x += r0.x; e0.y += r0.y; e0.z += r0.z; e0.w += r0.w;
            e1.x += r1.x; e1.y += r1.y; e1.z += r1.z; e1.w += r1.w;
            e2.x += r2.x; e2.y += r2.y; e2.z += r2.z; e2.w += r2.w;
            e3.x += r3.x; e3.y += r3.y; e3.z += r3.z; e3.w += r3.w;
            *(s8*)(dst + 16 * sub)     = pack8(e0, e1);
            *(s8*)(dst + 16 * sub + 8) = pack8(e2, e3);
            const float4 t0 = tp[b4 + 0], t1 = tp[b4 + 1], t2 = tp[b4 + 2], t3 = tp[b4 + 3];
            partial = e0.x*t0.x + e0.y*t0.y + e0.z*t0.z + e0.w*t0.w
                    + e1.x*t1.x + e1.y*t1.y + e1.z*t1.z + e1.w*t1.w
                    + e2.x*t2.x + e2.y*t2.y + e2.z*t2.z + e2.w*t2.w
                    + e3.x*t3.x + e3.y*t3.y + e3.z*t3.z + e3.w*t3.w;
        } else if (sub == 6) {
            float4 e = hp[24];
            const float4 r0 = rv[24];
            e.x += r0.x; e.y += r0.y; e.z += r0.z; e.w += r0.w;
            const float bias = rp.bias[t];
            s8 v = { (short)bf16_rne(e.x), (short)bf16_rne(e.y),
                     (short)bf16_rne(e.z), (short)bf16_rne(e.w),
                     (short)bf16_rne(bias), 0, 0, 0 };
            *(s8*)(dst + 96) = v;
            const float4 t0 = tp[24];
            partial = e.x*t0.x + e.y*t0.y + e.z*t0.z + e.w*t0.w + bias;
        } else {
            s8 z = {0,0,0,0,0,0,0,0};
            *(s8*)(dst + 104) = z;
            *(s8*)(dst + 120) = z;
        }

        // width-8 reduce -> row leader has pos = dot + bias
        partial += __shfl_down(partial, 4, 8);
        partial += __shfl_down(partial, 2, 8);
        partial += __shfl_down(partial, 1, 8);
        if (sub == 0) atomicAdd(&psum, softplus_f(-partial));
        __syncthreads();
        if (tid == 0) atomicAdd(p.out, psum * (1.0f / BATCH));
    } else {
        // ---- B-table: 32 rows/block, 8 threads/row ----
        const int row = (blk - 1024) * 32 + (tid >> 3);   // [rel*256 + neg]
        const int r   = row >> 8;
        const int n   = p.neg_idxs[r * NUM_NEG + (row & 255)];
        const float4* sp = (const float4*)(p.rel[r].tail + (size_t)n * EMBED);
        short* dst = bws + (size_t)row * PITCH;

        if (sub < 6) {
            const int b4 = sub * 4;
            *(s8*)(dst + 16 * sub)     = pack8(sp[b4 + 0], sp[b4 + 1]);
            *(s8*)(dst + 16 * sub + 8) = pack8(sp[b4 + 2], sp[b4 + 3]);
        } else if (sub == 6) {
            const float4 f = sp[24];
            s8 v = { (short)bf16_rne(f.x), (short)bf16_rne(f.y),
                     (short)bf16_rne(f.z), (short)bf16_rne(f.w),
                     (short)0x3F80, 0, 0, 0 };       // k100 = bf16(1.0)
            *(s8*)(dst + 96) = v;
        } else {
            s8 z = {0,0,0,0,0,0,0,0};
            *(s8*)(dst + 104) = z;
            *(s8*)(dst + 120) = z;
        }
    }
}

// ---- phase 2: GEMM + softplus-sum; staging = contiguous copies ----
__launch_bounds__(256, 3)
__global__ void ke_main(Params p, const short* aws, const short* bws) {
    // grid: 8 rel * 64 rowblocks * 2 negblocks = 1024
    const int bid = blockIdx.x;
    const int r   = bid & 7;
    const int rb  = (bid >> 3) & 63;
    const int nb  = bid >> 9;
    const int tid = threadIdx.x;

    __shared__ __align__(16) short As[BM * PITCH];   // 17408 B
    __shared__ __align__(16) short Bs[BN * PITCH];   // 34816 B

    // contiguous staging: A = 1088 s8, B = 2176 s8, 16 B/lane
    {
        const s8* asrc = (const s8*)(aws + (size_t)(r * 4096 + rb * BM) * PITCH);
        s8* adst = (s8*)As;
#pragma unroll
        for (int j = 0; j < 4; ++j)
            adst[tid + 256 * j] = asrc[tid + 256 * j];
        if (tid < 64) adst[1024 + tid] = asrc[1024 + tid];

        const s8* bsrc = (const s8*)(bws + (size_t)(r * NUM_NEG + nb * BN) * PITCH);
        s8* bdst = (s8*)Bs;
#pragma unroll
        for (int j = 0; j < 8; ++j)
            bdst[tid + 256 * j] = bsrc[tid + 256 * j];
        if (tid < 128) bdst[2048 + tid] = bsrc[2048 + tid];
    }
    __syncthreads();

    // ---- MFMA: 4 waves, wave tile 32 rows x 64 negs ----
    const int wave = tid >> 6;
    const int lane = tid & 63;
    const int li   = lane & 15;
    const int q    = lane >> 4;
    const int wm   = wave & 1;
    const int wn   = wave >> 1;

    f4 acc[2][4];
#pragma unroll
    for (int i = 0; i < 2; ++i)
#pragma unroll
        for (int j = 0; j < 4; ++j)
            acc[i][j] = (f4){0.f, 0.f, 0.f, 0.f};

    const short* Abase = As + (wm * 32 + li) * PITCH + q * 8;
    const short* Bbase = Bs + (wn * 64 + li) * PITCH + q * 8;

#pragma unroll
    for (int s = 0; s < 4; ++s) {
        const s8 a0 = *(const s8*)(Abase +  0 * PITCH + s * 32);
        const s8 a1 = *(const s8*)(Abase + 16 * PITCH + s * 32);
        const s8 b0 = *(const s8*)(Bbase +  0 * PITCH + s * 32);
        const s8 b1 = *(const s8*)(Bbase + 16 * PITCH + s * 32);
        const s8 b2 = *(const s8*)(Bbase + 32 * PITCH + s * 32);
        const s8 b3 = *(const s8*)(Bbase + 48 * PITCH + s * 32);
        acc[0][0] = __builtin_amdgcn_mfma_f32_16x16x32_bf16(a0, b0, acc[0][0], 0, 0, 0);
        acc[0][1] = __builtin_amdgcn_mfma_f32_16x16x32_bf16(a0, b1, acc[0][1], 0, 0, 0);
        acc[0][2] = __builtin_amdgcn_mfma_f32_16x16x32_bf16(a0, b2, acc[0][2], 0, 0, 0);
        acc[0][3] = __builtin_amdgcn_mfma_f32_16x16x32_bf16(a0, b3, acc[0][3], 0, 0, 0);
        acc[1][0] = __builtin_amdgcn_mfma_f32_16x16x32_bf16(a1, b0, acc[1][0], 0, 0, 0);
        acc[1][1] = __builtin_amdgcn_mfma_f32_16x16x32_bf16(a1, b1, acc[1][1], 0, 0, 0);
        acc[1][2] = __builtin_amdgcn_mfma_f32_16x16x32_bf16(a1, b2, acc[1][2], 0, 0, 0);
        acc[1][3] = __builtin_amdgcn_mfma_f32_16x16x32_bf16(a1, b3, acc[1][3], 0, 0, 0);
    }

    // ---- epilogue: softplus-sum (bias folded into acc) ----
    float local = 0.0f;
#pragma unroll
    for (int i = 0; i < 2; ++i)
#pragma unroll
        for (int j = 0; j < 4; ++j) {
            local += softplus_f(acc[i][j].x);
            local += softplus_f(acc[i][j].y);
            local += softplus_f(acc[i][j].z);
            local += softplus_f(acc[i][j].w);
        }

    // ---- reduction ----
#pragma unroll
    for (int off = 32; off > 0; off >>= 1)
        local += __shfl_down(local, off, 64);

    __syncthreads();
    float* wsum = (float*)Bs;
    if (lane == 0) wsum[wave] = local;
    __syncthreads();
    if (tid == 0) {
        const float s = (wsum[0] + wsum[1]) + (wsum[2] + wsum[3]);
        atomicAdd(p.out, s * (1.0f / BATCH));
    }
}

extern "C" void kernel_launch(void* const* d_in, const int* in_sizes, int n_in,
                              void* d_out, int out_size, void* d_ws, size_t ws_size,
                              hipStream_t stream) {
    const float* user  = (const float*)d_in[0];
    const float* prod  = (const float*)d_in[1];
    const float* word  = (const float*)d_in[2];
    const float* brand = (const float*)d_in[3];
    const float* cat   = (const float*)d_in[4];
    const float* rprod = (const float*)d_in[5];

    Params p;
    p.rel_vecs   = (const float*)d_in[6];
    p.batch_idxs = (const int*)d_in[15];
    p.neg_idxs   = (const int*)d_in[16];
    p.out        = (float*)d_out;

    p.rel[0] = {user, prod,  (const float*)d_in[7],  0, 1};  // purchase
    p.rel[1] = {user, word,  (const float*)d_in[8],  0, 2};  // mentions
    p.rel[2] = {prod, word,  (const float*)d_in[9],  1, 2};  // describe
    p.rel[3] = {prod, brand, (const float*)d_in[10], 1, 3};  // produced
    p.rel[4] = {prod, cat,   (const float*)d_in[11], 1, 4};  // belongs
    p.rel[5] = {prod, rprod, (const float*)d_in[12], 1, 5};  // also_bought
    p.rel[6] = {prod, rprod, (const float*)d_in[13], 1, 6};  // also_viewed
    p.rel[7] = {prod, rprod, (const float*)d_in[14], 1, 7};  // together

    short* aws = (short*)d_ws;                       // 32768 * 136 shorts
    short* bws = aws + (size_t)32768 * PITCH;        // 2048 * 136 shorts

    hipMemsetAsync(d_out, 0, sizeof(float), stream);
    ke_prep<<<1088, 256, 0, stream>>>(p, aws, bws);
    ke_main<<<1024, 256, 0, stream>>>(p, aws, bws);
}

// Round 12
// 153.139 us; speedup vs baseline: 1.1098x; 1.1098x over previous
//
#include <hip/hip_runtime.h>

// KnowledgeEmbedding loss via bf16 MFMA GEMM, single phase (two-phase R10/R11
// cost +14 us of dispatch serialization -- abandoned).
// score(row,neg) = dot(head[h]+rvec, tail[neg]) + bias[t]; loss = mean softplus sum.
//
// R7 shape: block = 128 rows x 128 negs, K=100 padded 128, grid 8*32*2 = 512,
// LDS 64 KB (2 blocks/CU), wave tile 64x64. NEW: XOR chunk swizzle fixes the
// PITCH=128 bank pileup R8 measured (5.9M conflict cycles): 16B chunk c of row
// r lives at chunk slot c^(r&7). Frag reads hit bank group 4*((q+4s)^(li&7))
// -> all 8 groups uniform (2 lanes/bank = free); staging writes identical.
// Bias folded at k=100 (A=bias, B=1.0) -> layout-agnostic softplus-sum.
// Pos term: nb==0 blocks, threads 128..255 decode ex from swizzled As (no
// head re-gather), gather tail fp32 only.

#define EMBED   100
#define BATCH   4096
#define NUM_NEG 256
#define BM      128
#define BN      128
#define PITCH   128   // shorts per row; conflicts handled by XOR swizzle

typedef __attribute__((ext_vector_type(8))) short s8;
typedef __attribute__((ext_vector_type(4))) float f4;

struct RelP {
    const float* head;
    const float* tail;
    const float* bias;
    int hc, tc;
};

struct Params {
    RelP rel[8];
    const float* rel_vecs;
    const int*   batch_idxs;
    const int*   neg_idxs;
    float*       out;
};

__device__ __forceinline__ float softplus_f(float x) {
    float e = __expf(-fabsf(x));
    return fmaxf(x, 0.0f) + __logf(1.0f + e);
}

__device__ __forceinline__ unsigned short bf16_rne(float f) {
    unsigned u = __float_as_uint(f);
    u += 0x7FFFu + ((u >> 16) & 1u);
    return (unsigned short)(u >> 16);
}

__device__ __forceinline__ float bf16_to_f(short s) {
    return __uint_as_float(((unsigned)(unsigned short)s) << 16);
}

__device__ __forceinline__ s8 pack8(float4 f0, float4 f1) {
    s8 v = { (short)bf16_rne(f0.x), (short)bf16_rne(f0.y),
             (short)bf16_rne(f0.z), (short)bf16_rne(f0.w),
             (short)bf16_rne(f1.x), (short)bf16_rne(f1.y),
             (short)bf16_rne(f1.z), (short)bf16_rne(f1.w) };
    return v;
}

__launch_bounds__(256, 2)
__global__ void ke_kernel(Params p) {
    // grid: 8 rel * 32 rowblocks * 2 negblocks = 512
    const int bid = blockIdx.x;
    const int r   = bid & 7;
    const int rb  = (bid >> 3) & 31;
    const int nb  = bid >> 8;            // 0..1
    const int tid = threadIdx.x;

    __shared__ __align__(16) short As[BM * PITCH];   // 32 KB, chunk-swizzled
    __shared__ __align__(16) short Bs[BN * PITCH];   // 32 KB, chunk-swizzled

    const RelP rp = p.rel[r];

    // ---- staging: thread t owns one full row (t<128: A row; else B row) ----
    {
        const bool isA = tid < BM;
        const int  row = isA ? tid : (tid - BM);
        const int  sw  = row & 7;
        const float* src;
        unsigned short extra;            // k=100 payload
        short* dst;
        if (isA) {
            const int grow = rb * BM + row;
            const int h  = p.batch_idxs[grow * 8 + rp.hc];
            const int ti = p.batch_idxs[grow * 8 + rp.tc];
            src   = rp.head + (size_t)h * EMBED;
            extra = bf16_rne(rp.bias[ti]);
            dst   = As + row * PITCH;
        } else {
            const int n = p.neg_idxs[r * NUM_NEG + nb * BN + row];
            src   = rp.tail + (size_t)n * EMBED;
            extra = 0x3F80;              // bf16(1.0)
            dst   = Bs + row * PITCH;
        }
        const float4* s4p = (const float4*)src;
        const float4* rv4 = (const float4*)(p.rel_vecs + r * EMBED);

#pragma unroll
        for (int c = 0; c < 12; ++c) {   // chunks 0..11 = floats 0..95
            float4 f0 = s4p[2 * c];
            float4 f1 = s4p[2 * c + 1];
            if (isA) {
                const float4 a = rv4[2 * c];
                const float4 b = rv4[2 * c + 1];
                f0.x += a.x; f0.y += a.y; f0.z += a.z; f0.w += a.w;
                f1.x += b.x; f1.y += b.y; f1.z += b.z; f1.w += b.w;
            }
            *(s8*)(dst + 8 * (c ^ sw)) = pack8(f0, f1);
        }
        {   // chunk 12: floats 96..99, extra at k=100, zeros 101..103
            float4 f = s4p[24];
            if (isA) {
                const float4 a = rv4[24];
                f.x += a.x; f.y += a.y; f.z += a.z; f.w += a.w;
            }
            s8 v = { (short)bf16_rne(f.x), (short)bf16_rne(f.y),
                     (short)bf16_rne(f.z), (short)bf16_rne(f.w),
                     (short)extra, 0, 0, 0 };
            *(s8*)(dst + 8 * (12 ^ sw)) = v;
        }
        {   // chunks 13..15: zeros (k=104..127)
            s8 z = {0,0,0,0,0,0,0,0};
            *(s8*)(dst + 8 * (13 ^ sw)) = z;
            *(s8*)(dst + 8 * (14 ^ sw)) = z;
            *(s8*)(dst + 8 * (15 ^ sw)) = z;
        }
    }

    // pos-term prep (loads issued before barrier): threads 128..255, nb==0
    const bool doPos = (nb == 0) && (tid >= BM);
    const float* ptail = rp.tail;
    float pbias = 0.0f;
    if (doPos) {
        const int prow = rb * BM + (tid - BM);
        const int pt = p.batch_idxs[prow * 8 + rp.tc];
        ptail = rp.tail + (size_t)pt * EMBED;
        pbias = rp.bias[pt];
    }

    __syncthreads();

    // ---- MFMA: 4 waves, wave tile 64x64 (4x4 of 16x16x32, 4 k-steps) ----
    const int wave = tid >> 6;
    const int lane = tid & 63;
    const int li   = lane & 15;
    const int q    = lane >> 4;
    const int wm   = wave >> 1;          // row half
    const int wn   = wave & 1;           // neg half
    const int sw   = li & 7;             // swizzle key (row & 7 == li & 7)

    f4 acc[4][4];
#pragma unroll
    for (int i = 0; i < 4; ++i)
#pragma unroll
        for (int j = 0; j < 4; ++j)
            acc[i][j] = (f4){0.f, 0.f, 0.f, 0.f};

    const short* Abase = As + (wm * 64 + li) * PITCH;
    const short* Bbase = Bs + (wn * 64 + li) * PITCH;

#pragma unroll
    for (int s = 0; s < 4; ++s) {
        const int co = 8 * ((q + 4 * s) ^ sw);       // swizzled chunk offset
        const s8 a0 = *(const s8*)(Abase +  0 * PITCH + co);
        const s8 a1 = *(const s8*)(Abase + 16 * PITCH + co);
        const s8 a2 = *(const s8*)(Abase + 32 * PITCH + co);
        const s8 a3 = *(const s8*)(Abase + 48 * PITCH + co);
        const s8 b0 = *(const s8*)(Bbase +  0 * PITCH + co);
        const s8 b1 = *(const s8*)(Bbase + 16 * PITCH + co);
        const s8 b2 = *(const s8*)(Bbase + 32 * PITCH + co);
        const s8 b3 = *(const s8*)(Bbase + 48 * PITCH + co);
        acc[0][0] = __builtin_amdgcn_mfma_f32_16x16x32_bf16(a0, b0, acc[0][0], 0, 0, 0);
        acc[0][1] = __builtin_amdgcn_mfma_f32_16x16x32_bf16(a0, b1, acc[0][1], 0, 0, 0);
        acc[0][2] = __builtin_amdgcn_mfma_f32_16x16x32_bf16(a0, b2, acc[0][2], 0, 0, 0);
        acc[0][3] = __builtin_amdgcn_mfma_f32_16x16x32_bf16(a0, b3, acc[0][3], 0, 0, 0);
        acc[1][0] = __builtin_amdgcn_mfma_f32_16x16x32_bf16(a1, b0, acc[1][0], 0, 0, 0);
        acc[1][1] = __builtin_amdgcn_mfma_f32_16x16x32_bf16(a1, b1, acc[1][1], 0, 0, 0);
        acc[1][2] = __builtin_amdgcn_mfma_f32_16x16x32_bf16(a1, b2, acc[1][2], 0, 0, 0);
        acc[1][3] = __builtin_amdgcn_mfma_f32_16x16x32_bf16(a1, b3, acc[1][3], 0, 0, 0);
        acc[2][0] = __builtin_amdgcn_mfma_f32_16x16x32_bf16(a2, b0, acc[2][0], 0, 0, 0);
        acc[2][1] = __builtin_amdgcn_mfma_f32_16x16x32_bf16(a2, b1, acc[2][1], 0, 0, 0);
        acc[2][2] = __builtin_amdgcn_mfma_f32_16x16x32_bf16(a2, b2, acc[2][2], 0, 0, 0);
        acc[2][3] = __builtin_amdgcn_mfma_f32_16x16x32_bf16(a2, b3, acc[2][3], 0, 0, 0);
        acc[3][0] = __builtin_amdgcn_mfma_f32_16x16x32_bf16(a3, b0, acc[3][0], 0, 0, 0);
        acc[3][1] = __builtin_amdgcn_mfma_f32_16x16x32_bf16(a3, b1, acc[3][1], 0, 0, 0);
        acc[3][2] = __builtin_amdgcn_mfma_f32_16x16x32_bf16(a3, b2, acc[3][2], 0, 0, 0);
        acc[3][3] = __builtin_amdgcn_mfma_f32_16x16x32_bf16(a3, b3, acc[3][3], 0, 0, 0);
    }

    // ---- epilogue: softplus-sum (bias folded into acc) ----
    float local = 0.0f;
#pragma unroll
    for (int i = 0; i < 4; ++i)
#pragma unroll
        for (int j = 0; j < 4; ++j) {
            local += softplus_f(acc[i][j].x);
            local += softplus_f(acc[i][j].y);
            local += softplus_f(acc[i][j].z);
            local += softplus_f(acc[i][j].w);
        }

    // ---- positive term: ex decoded from swizzled As, tail fp32 gather ----
    if (doPos) {
        const int prow = tid - BM;
        const int psw  = prow & 7;
        const short* exr = As + prow * PITCH;
        const float4* tv = (const float4*)ptail;
        float d0 = 0.f, d1 = 0.f, d2 = 0.f, d3 = 0.f;
#pragma unroll
        for (int c = 0; c < 12; ++c) {
            const s8 e = *(const s8*)(exr + 8 * (c ^ psw));
            const float4 t0 = tv[2 * c];
            const float4 t1 = tv[2 * c + 1];
            d0 = fmaf(bf16_to_f(e[0]), t0.x, d0);
            d1 = fmaf(bf16_to_f(e[1]), t0.y, d1);
            d2 = fmaf(bf16_to_f(e[2]), t0.z, d2);
            d3 = fmaf(bf16_to_f(e[3]), t0.w, d3);
            d0 = fmaf(bf16_to_f(e[4]), t1.x, d0);
            d1 = fmaf(bf16_to_f(e[5]), t1.y, d1);
            d2 = fmaf(bf16_to_f(e[6]), t1.z, d2);
            d3 = fmaf(bf16_to_f(e[7]), t1.w, d3);
        }
        {
            const s8 e = *(const s8*)(exr + 8 * (12 ^ psw));
            const float4 t0 = tv[24];
            d0 = fmaf(bf16_to_f(e[0]), t0.x, d0);
            d1 = fmaf(bf16_to_f(e[1]), t0.y, d1);
            d2 = fmaf(bf16_to_f(e[2]), t0.z, d2);
            d3 = fmaf(bf16_to_f(e[3]), t0.w, d3);
        }
        const float pos = ((d0 + d1) + (d2 + d3)) + pbias;
        local += softplus_f(-pos);
    }

    // ---- reduction ----
#pragma unroll
    for (int off = 32; off > 0; off >>= 1)
        local += __shfl_down(local, off, 64);

    __syncthreads();                     // all As/Bs reads done -> safe to alias
    float* wsum = (float*)Bs;
    const int lane2 = tid & 63;
    if (lane2 == 0) wsum[tid >> 6] = local;
    __syncthreads();
    if (tid == 0) {
        const float s = (wsum[0] + wsum[1]) + (wsum[2] + wsum[3]);
        atomicAdd(p.out, s * (1.0f / BATCH));
    }
}

extern "C" void kernel_launch(void* const* d_in, const int* in_sizes, int n_in,
                              void* d_out, int out_size, void* d_ws, size_t ws_size,
                              hipStream_t stream) {
    const float* user  = (const float*)d_in[0];
    const float* prod  = (const float*)d_in[1];
    const float* word  = (const float*)d_in[2];
    const float* brand = (const float*)d_in[3];
    const float* cat   = (const float*)d_in[4];
    const float* rprod = (const float*)d_in[5];

    Params p;
    p.rel_vecs   = (const float*)d_in[6];
    p.batch_idxs = (const int*)d_in[15];
    p.neg_idxs   = (const int*)d_in[16];
    p.out        = (float*)d_out;

    p.rel[0] = {user, prod,  (const float*)d_in[7],  0, 1};  // purchase
    p.rel[1] = {user, word,  (const float*)d_in[8],  0, 2};  // mentions
    p.rel[2] = {prod, word,  (const float*)d_in[9],  1, 2};  // describe
    p.rel[3] = {prod, brand, (const float*)d_in[10], 1, 3};  // produced
    p.rel[4] = {prod, cat,   (const float*)d_in[11], 1, 4};  // belongs
    p.rel[5] = {prod, rprod, (const float*)d_in[12], 1, 5};  // also_bought
    p.rel[6] = {prod, rprod, (const float*)d_in[13], 1, 6};  // also_viewed
    p.rel[7] = {prod, rprod, (const float*)d_in[14], 1, 7};  // together

    hipMemsetAsync(d_out, 0, sizeof(float), stream);
    ke_kernel<<<512, 256, 0, stream>>>(p);
}